// Round 3
// baseline (354.617 us; speedup 1.0000x reference)
//
#include <hip/hip_runtime.h>
#include <hip/hip_bf16.h>

// ProjectionPursuitProbe: h' = scale * (h - P G^{-1} P^T h), G = P^T P
// B=8, S=4096, F=1024, R=64. Rows N = 32768.
//
// R3: K-split decomposition. Block = 16 rows, 4 waves. Wave w:
//   phase1: partial Y over k in [w*256,+256)  -> LDS reduce (fp32)
//   phase2: C tile n in [w*16,+16)            -> LDS
//   phase3: out f in [w*256,+256)
// Grid 2048 blocks -> 8192 waves (32/CU demand), LDS 21.8KB -> 7 blocks/CU.

typedef __attribute__((ext_vector_type(8))) short bf16x8;
typedef __attribute__((ext_vector_type(4))) float f32x4;

#define MFMA_B16(a, b, c) __builtin_amdgcn_mfma_f32_16x16x32_bf16((a), (b), (c), 0, 0, 0)

__device__ __forceinline__ unsigned short bf16bits(float x) {
  union { float f; unsigned u; } v; v.f = x;
  return (unsigned short)((v.u + 0x7fffu + ((v.u >> 16) & 1u)) >> 16);  // RNE
}

__device__ __forceinline__ bf16x8 packbf8(f32x4 v0, f32x4 v1) {
  union { bf16x8 v; __hip_bfloat162 h[4]; } u;
  u.h[0] = __float22bfloat162_rn(make_float2(v0[0], v0[1]));
  u.h[1] = __float22bfloat162_rn(make_float2(v0[2], v0[3]));
  u.h[2] = __float22bfloat162_rn(make_float2(v1[0], v1[1]));
  u.h[3] = __float22bfloat162_rn(make_float2(v1[2], v1[3]));
  return u.v;
}

__device__ __forceinline__ bf16x8 cvt8(const float* p) {  // 8 LDS floats -> bf16x8
  return packbf8(*(const f32x4*)p, *(const f32x4*)(p + 4));
}
__device__ __forceinline__ float dot4(f32x4 a, f32x4 b) {
  return a[0] * b[0] + a[1] * b[1] + a[2] * b[2] + a[3] * b[3];
}

// ---------------- K1: gram partials + pack P to bf16 (Ptb r-major, Pb f-major) ----------
__global__ void pp_prep(const float* __restrict__ P, float* __restrict__ partial,
                        unsigned short* __restrict__ Ptb, unsigned short* __restrict__ Pb) {
  __shared__ float Pl[64][68];
  const int tid = threadIdx.x, ch = blockIdx.x;
  #pragma unroll
  for (int u = 0; u < 4; ++u) {
    const int f = tid >> 2, r = (tid & 3) * 16 + 4 * u;
    *(f32x4*)&Pl[f][r] = *(const f32x4*)(P + (size_t)(ch * 64 + f) * 64 + r);
  }
  __syncthreads();
  const int a0 = (tid >> 4) * 4, b0 = (tid & 15) * 4;
  f32x4 acc[4];
  #pragma unroll
  for (int i = 0; i < 4; ++i) acc[i] = (f32x4){0.f, 0.f, 0.f, 0.f};
  for (int k = 0; k < 64; ++k) {
    f32x4 av = *(const f32x4*)&Pl[k][a0];
    f32x4 bv = *(const f32x4*)&Pl[k][b0];
    #pragma unroll
    for (int i = 0; i < 4; ++i) acc[i] += av[i] * bv;
  }
  #pragma unroll
  for (int i = 0; i < 4; ++i)
    *(f32x4*)(partial + (size_t)ch * 4096 + (size_t)(a0 + i) * 64 + b0) = acc[i];
  const int f = tid >> 2, c0 = (tid & 3) * 16;
  const int gf = ch * 64 + f;
  unsigned short b16[16];
  #pragma unroll
  for (int u = 0; u < 16; ++u) b16[u] = bf16bits(Pl[f][c0 + u]);
  #pragma unroll
  for (int u = 0; u < 16; ++u) Ptb[(size_t)(c0 + u) * 1024 + gf] = b16[u];
  #pragma unroll
  for (int w = 0; w < 4; ++w) {
    unsigned long long q = (unsigned long long)b16[4 * w] |
                           ((unsigned long long)b16[4 * w + 1] << 16) |
                           ((unsigned long long)b16[4 * w + 2] << 32) |
                           ((unsigned long long)b16[4 * w + 3] << 48);
    *(unsigned long long*)(Pb + (size_t)gf * 64 + c0 + 4 * w) = q;
  }
}

// ---------------- K2: G = sum partials; Wb = bf16(G^{-1}) via Gauss-Jordan (SPD) ----------
__global__ void pp_invert(const float* __restrict__ partial, unsigned short* __restrict__ Wb) {
  __shared__ float A[64][68];
  const int tid = threadIdx.x;
  const int i = tid >> 2, q16 = (tid & 3) * 16;
  #pragma unroll
  for (int u = 0; u < 4; ++u) {
    f32x4 s = (f32x4){0.f, 0.f, 0.f, 0.f};
    const int off = i * 64 + q16 + 4 * u;
    for (int p = 0; p < 16; ++p) s += *(const f32x4*)(partial + (size_t)p * 4096 + off);
    *(f32x4*)&A[i][q16 + 4 * u] = s;
  }
  __syncthreads();
  for (int k = 0; k < 64; ++k) {
    const float d = 1.0f / A[k][k];
    const float f = A[i][k];
    f32x4 prs[4], cur[4];
    #pragma unroll
    for (int u = 0; u < 4; ++u) {
      prs[u] = *(const f32x4*)&A[k][q16 + 4 * u];
      cur[u] = *(const f32x4*)&A[i][q16 + 4 * u];
    }
    __syncthreads();
    const int kl = k - q16;
    #pragma unroll
    for (int u = 0; u < 4; ++u) {
      f32x4 pv = prs[u] * d;
      if (kl >= u * 4 && kl < u * 4 + 4) { pv[kl - u * 4] = d; cur[u][kl - u * 4] = 0.f; }
      f32x4 res = (i == k) ? pv : (cur[u] - f * pv);
      *(f32x4*)&A[i][q16 + 4 * u] = res;
    }
    __syncthreads();
  }
  #pragma unroll
  for (int u = 0; u < 4; ++u) {
    #pragma unroll
    for (int j = 0; j < 4; ++j) Wb[(size_t)i * 64 + q16 + 4 * u + j] = bf16bits(A[i][q16 + 4 * u + j]);
  }
}

// ---------------- K3: fused main, 16 rows/block, 4 waves split K / N / F ----------------
__global__ __launch_bounds__(256, 7) void pp_main(
    const float* __restrict__ H, const unsigned short* __restrict__ Ptb,
    const unsigned short* __restrict__ Pb, const unsigned short* __restrict__ Wb,
    float* __restrict__ out) {
  __shared__ float Yp[4][16][68];  // per-wave Y partials (fp32)
  __shared__ float Cl[16][68];     // C = Y @ W (fp32)
  __shared__ float rowsq[16];

  const int tid = threadIdx.x, wid = tid >> 6, lane = tid & 63;
  const int c16 = lane & 15, quad = lane >> 4;
  const unsigned row0 = (unsigned)blockIdx.x * 16;

  if (tid < 16) rowsq[tid] = 0.f;
  __syncthreads();  // barrier A (cheap: nothing in flight)

  // ---- phase 1: partial Y = H @ P over k in [wid*256, +256); + partial row sum-sq ----
  const float* hrow = H + (size_t)(row0 + c16) * 1024 + wid * 256 + quad * 8;
  const unsigned short* pB = Ptb + (size_t)c16 * 1024 + wid * 256 + quad * 8;
  f32x4 accY[4];
  #pragma unroll
  for (int t = 0; t < 4; ++t) accY[t] = (f32x4){0.f, 0.f, 0.f, 0.f};
  float sq = 0.f;
  #pragma unroll
  for (int kk = 0; kk < 8; ++kk) {
    f32x4 v0 = *(const f32x4*)(hrow + kk * 32);
    f32x4 v1 = *(const f32x4*)(hrow + kk * 32 + 4);
    sq += dot4(v0, v0) + dot4(v1, v1);
    bf16x8 a = packbf8(v0, v1);
    #pragma unroll
    for (int t = 0; t < 4; ++t) {
      bf16x8 b = *(const bf16x8*)(pB + (size_t)t * 16 * 1024 + kk * 32);
      accY[t] = MFMA_B16(a, b, accY[t]);
    }
  }
  sq += __shfl_xor(sq, 16, 64);
  sq += __shfl_xor(sq, 32, 64);  // per-row (c16) partial over this wave's k-slice
  if (lane < 16) atomicAdd(&rowsq[c16], sq);
  #pragma unroll
  for (int t = 0; t < 4; ++t)
    #pragma unroll
    for (int r = 0; r < 4; ++r)  // D: row = quad*4+r, col = c16
      Yp[wid][quad * 4 + r][t * 16 + c16] = accY[t][r];
  __syncthreads();  // barrier B: Yp + rowsq complete

  // ---- phase 2: wave wid computes C tile n in [wid*16,+16); keep fp32 Y row slices ----
  f32x4 ys0a = {0.f,0.f,0.f,0.f}, ys0b = {0.f,0.f,0.f,0.f};
  f32x4 ys1a = {0.f,0.f,0.f,0.f}, ys1b = {0.f,0.f,0.f,0.f};
  #pragma unroll
  for (int w2 = 0; w2 < 4; ++w2) {
    ys0a += *(const f32x4*)&Yp[w2][c16][quad * 8];
    ys0b += *(const f32x4*)&Yp[w2][c16][quad * 8 + 4];
    ys1a += *(const f32x4*)&Yp[w2][c16][32 + quad * 8];
    ys1b += *(const f32x4*)&Yp[w2][c16][32 + quad * 8 + 4];
  }
  bf16x8 ya0 = packbf8(ys0a, ys0b);   // A[m=c16][k=quad*8+j], k in [0,32)
  bf16x8 ya1 = packbf8(ys1a, ys1b);   // k in [32,64)
  const unsigned short* wB = Wb + (size_t)(wid * 16 + c16) * 64 + quad * 8;
  f32x4 accC = (f32x4){0.f, 0.f, 0.f, 0.f};
  accC = MFMA_B16(ya0, *(const bf16x8*)wB, accC);
  accC = MFMA_B16(ya1, *(const bf16x8*)(wB + 32), accC);
  #pragma unroll
  for (int r = 0; r < 4; ++r) Cl[quad * 4 + r][wid * 16 + c16] = accC[r];
  const float o2 = rowsq[c16];  // finalized at barrier B
  __syncthreads();  // barrier C: Cl complete

  // ---- per-row dot = y.c (redundant per wave, fp32) -> scale ----
  float d = dot4(ys0a, *(const f32x4*)&Cl[c16][quad * 8]) +
            dot4(ys0b, *(const f32x4*)&Cl[c16][quad * 8 + 4]) +
            dot4(ys1a, *(const f32x4*)&Cl[c16][32 + quad * 8]) +
            dot4(ys1b, *(const f32x4*)&Cl[c16][32 + quad * 8 + 4]);
  d += __shfl_xor(d, 16, 64);
  d += __shfl_xor(d, 32, 64);
  const float scl = sqrtf(o2 / fmaxf(o2 - d, 1e-30f));  // scale for row c16

  // ---- phase 3: out = (H - C @ P^T) * scale over f in [wid*256,+256) ----
  bf16x8 ca0 = cvt8(&Cl[c16][quad * 8]);
  bf16x8 ca1 = cvt8(&Cl[c16][32 + quad * 8]);
  float sc[4]; unsigned rg[4]; bool fs[4];
  #pragma unroll
  for (int r = 0; r < 4; ++r) {
    const int m = quad * 4 + r;
    sc[r] = __shfl(scl, m, 64);  // lane m has c16 == m
    rg[r] = row0 + m;
    fs[r] = ((rg[r] & 4095u) == 0u);  // s == 0 rows pass through exactly
  }
  const unsigned short* pb3 = Pb + ((size_t)wid * 16 * 16 + c16) * 64 + quad * 8;
  #pragma unroll 4
  for (int ft = 0; ft < 16; ++ft) {
    bf16x8 b0 = *(const bf16x8*)(pb3 + (size_t)ft * 16 * 64);       // B[k=r][n=f]
    bf16x8 b1 = *(const bf16x8*)(pb3 + (size_t)ft * 16 * 64 + 32);
    f32x4 acc = (f32x4){0.f, 0.f, 0.f, 0.f};
    acc = MFMA_B16(ca0, b0, acc);
    acc = MFMA_B16(ca1, b1, acc);
    const unsigned f = (unsigned)(wid * 16 + ft) * 16 + c16;
    #pragma unroll
    for (int r = 0; r < 4; ++r) {
      const size_t idx = (size_t)rg[r] * 1024 + f;
      const float h = H[idx];  // re-read: L2/L3 hit (fetched in phase 1)
      const float o = fs[r] ? h : (h - acc[r]) * sc[r];
      __builtin_nontemporal_store(o, &out[idx]);
    }
  }
}

extern "C" void kernel_launch(void* const* d_in, const int* in_sizes, int n_in,
                              void* d_out, int out_size, void* d_ws, size_t ws_size,
                              hipStream_t stream) {
  const float* H = (const float*)d_in[0];  // 8*4096*1024 fp32
  const float* P = (const float*)d_in[1];  // 1024*64 fp32
  float* out = (float*)d_out;
  float* ws = (float*)d_ws;
  // ws: partial (16*4096 f32) | Ptb (65536 u16) | Pb (65536 u16) | Wb (4096 u16)
  float* partial = ws;
  unsigned short* Ptb = (unsigned short*)(ws + 16 * 4096);
  unsigned short* Pb = Ptb + 65536;
  unsigned short* Wb = Pb + 65536;

  pp_prep<<<16, 256, 0, stream>>>(P, partial, Ptb, Pb);
  pp_invert<<<1, 256, 0, stream>>>(partial, Wb);
  pp_main<<<2048, 256, 0, stream>>>(H, Ptb, Pb, Wb, out);
}